// Round 6
// baseline (8154.487 us; speedup 1.0000x reference)
//
#include <hip/hip_runtime.h>

typedef float f4 __attribute__((ext_vector_type(4)));

#define HID 256
#define AF 39
#define BF 11
#define EDGE_F 50          // AF + BF
#define OUT_F 295          // AF + HID
#define APM 20             // atoms per molecule (N/NM)
#define EPM 19             // tree edges per molecule (E/2/NM)
#define LEDGE 38           // directed edges per molecule

// Transposed weights live in module-global device memory (~0.6 MB):
// no d_ws dependency, no hipMalloc, rewritten every launch (replay-safe).
__device__ float g_WiT[EDGE_F * HID];   // [50][256]  = Wi^T
__device__ float g_WhT[HID * HID];      // [256][256] = Wh^T
__device__ float g_WoT[OUT_F * HID];    // [295][256] = Wo^T

__device__ __forceinline__ f4 relu4(f4 v) {
    f4 r;
    r[0] = fmaxf(v[0], 0.f); r[1] = fmaxf(v[1], 0.f);
    r[2] = fmaxf(v[2], 0.f); r[3] = fmaxf(v[3], 0.f);
    return r;
}

__global__ __launch_bounds__(256) void k_prep(const float* __restrict__ Wi,
                                              const float* __restrict__ Wh,
                                              const float* __restrict__ Wo) {
    const int NI = EDGE_F * HID, NH = HID * HID, NO = OUT_F * HID;
    int idx = blockIdx.x * 256 + threadIdx.x;
    if (idx < NI) {
        int k = idx / HID, h = idx % HID;
        g_WiT[idx] = Wi[h * EDGE_F + k];
    } else if (idx < NI + NH) {
        int j = idx - NI, k = j / HID, h = j % HID;
        g_WhT[j] = Wh[h * HID + k];
    } else if (idx < NI + NH + NO) {
        int j = idx - NI - NH, k = j / HID, h = j % HID;
        g_WoT[j] = Wo[h * OUT_F + k];
    }
}

// One block = one molecule. Messages live in registers (each thread: 5 rows x
// f4 cols tc, tc+32); LDS only for 16-f4-column chunked msg/node-sum exchange
// and weight-panel staging. LDS: A 41.6 KB + S 16.4 KB + topo ~0.6 KB = 58.6 KB.
__global__ __launch_bounds__(256) void k_mpnn(
        const float* __restrict__ x, const float* __restrict__ bx,
        const float* __restrict__ bo,
        const int* __restrict__ esrc, const int* __restrict__ edst,
        float* __restrict__ out, int Eh) {
    __shared__ __align__(16) float A[40 * 260];   // agg-A / B-stage (iter0) / A2(out, stride 300)
    __shared__ __align__(16) float S[16 * 256];   // feats / msg+ns chunks / B chunks / partials
    __shared__ int srcloc[LEDGE], dstloc[LEDGE], noff[APM + 1], nlist[LEDGE], ncnt[APM];

    const int tid = threadIdx.x;
    const int g = blockIdx.x;
    const int tr = tid >> 5;
    const int tc = tid & 31;
    f4* A4 = (f4*)A;
    f4* S4 = (f4*)S;

    // ---- local topology ----
    if (tid < EPM) {
        int e = g * EPM + tid;
        int s = esrc[e] - g * APM;       // child
        int d = edst[e] - g * APM;       // parent
        srcloc[tid] = s;        dstloc[tid] = d;
        srcloc[tid + EPM] = d;  dstloc[tid + EPM] = s;   // reverse edge
    }
    __syncthreads();
    if (tid == 0) {          // per-node in-edge lists (38 entries total)
        for (int v = 0; v < APM; ++v) ncnt[v] = 0;
        for (int r = 0; r < LEDGE; ++r) ncnt[dstloc[r]]++;
        noff[0] = 0;
        for (int v = 0; v < APM; ++v) noff[v + 1] = noff[v] + ncnt[v];
        for (int v = 0; v < APM; ++v) ncnt[v] = 0;
        for (int r = 0; r < LEDGE; ++r) {
            int v = dstloc[r];
            nlist[noff[v] + ncnt[v]++] = r;
        }
    }
    // ---- feats [38][50] into S (stride 52); nlist build overlaps (different arrays) ----
    for (int idx = tid; idx < LEDGE * EDGE_F; idx += 256) {
        int r = idx / EDGE_F, c = idx % EDGE_F;
        int ge = (r < EPM) ? g * EPM + r : Eh + g * EPM + (r - EPM);
        float v = (c < AF) ? x[(g * APM + srcloc[r]) * AF + c]
                           : bx[ge * BF + (c - AF)];
        S[r * 52 + c] = v;
    }
    __syncthreads();

    f4 acc0[5], acc1[5], mi0[5], mi1[5];
    #pragma unroll
    for (int i = 0; i < 5; ++i) { acc0[i] = f4{}; acc1[i] = f4{}; }

    // ---- iter 0: mi = feats @ Wi^T (B chunks staged in A region; feats stay in S) ----
    const f4* WiT4 = (const f4*)&g_WiT[0];
    for (int k0 = 0; k0 < EDGE_F; k0 += 16) {
        int klen = EDGE_F - k0; if (klen > 16) klen = 16;
        for (int idx = tid; idx < klen * 64; idx += 256)
            A4[idx] = WiT4[(k0 + (idx >> 6)) * 64 + (idx & 63)];
        __syncthreads();
        for (int kl = 0; kl < klen; ++kl) {
            f4 b0 = A4[kl * 64 + tc];
            f4 b1 = A4[kl * 64 + 32 + tc];
            #pragma unroll
            for (int i = 0; i < 5; ++i) {
                float a = S[(tr * 5 + i) * 52 + k0 + kl];
                acc0[i] += a * b0;
                acc1[i] += a * b1;
            }
        }
        __syncthreads();
    }
    #pragma unroll
    for (int i = 0; i < 5; ++i) { mi0[i] = acc0[i]; mi1[i] = acc1[i]; }

    // ---- iterations 1..5: msg = relu(mi + (ns[src]-msg[rev]) @ Wh^T) ----
    const f4* WhT4 = (const f4*)&g_WhT[0];
    f4* Sm = S4;                    // [38][16] f4 msg chunk
    f4* Sns = S4 + LEDGE * 16;      // [20][16] f4 node-sum chunk
    for (int it = 1; it <= 5; ++it) {
        // build agg A[38][256] (stride 260) in 4 column chunks of 16 f4 cols
        for (int ch = 0; ch < 4; ++ch) {
            if ((tc >> 4) == (ch & 1)) {          // this thread owns cols of this chunk
                int cc = tc & 15;
                #pragma unroll
                for (int i = 0; i < 5; ++i) {
                    int r = tr * 5 + i;
                    if (r < LEDGE) Sm[r * 16 + cc] = relu4(ch < 2 ? acc0[i] : acc1[i]);
                }
            }
            __syncthreads();
            for (int idx2 = tid; idx2 < APM * 16; idx2 += 256) {   // 320 items
                int v = idx2 >> 4, cc = idx2 & 15;
                f4 s = f4{};
                for (int j = noff[v]; j < noff[v + 1]; ++j)
                    s += Sm[nlist[j] * 16 + cc];
                Sns[v * 16 + cc] = s;
            }
            __syncthreads();
            for (int idx2 = tid; idx2 < LEDGE * 16; idx2 += 256) { // 608 items
                int r = idx2 >> 4, cc = idx2 & 15;
                int rev = (r < EPM) ? r + EPM : r - EPM;
                A4[r * 65 + ch * 16 + cc] = Sns[srcloc[r] * 16 + cc] - Sm[rev * 16 + cc];
            }
            __syncthreads();
        }
        #pragma unroll
        for (int i = 0; i < 5; ++i) { acc0[i] = mi0[i]; acc1[i] = mi1[i]; }
        // GEMM: acc += A @ Wh^T, K=256 in 16-row B chunks via S
        for (int kc = 0; kc < 16; ++kc) {
            #pragma unroll
            for (int j = 0; j < 4; ++j) {
                int idx = tid + j * 256;
                S4[idx] = WhT4[(kc * 16 + (idx >> 6)) * 64 + (idx & 63)];
            }
            __syncthreads();
            #pragma unroll 4
            for (int kl = 0; kl < 16; ++kl) {
                f4 b0 = S4[kl * 64 + tc];
                f4 b1 = S4[kl * 64 + 32 + tc];
                #pragma unroll
                for (int i = 0; i < 5; ++i) {
                    float a = A[(tr * 5 + i) * 260 + kc * 16 + kl];
                    acc0[i] += a * b0;
                    acc1[i] += a * b1;
                }
            }
            __syncthreads();
        }
    }

    // ---- output phase: A2[20][295] (stride 300) = [x | m], m = node-sum of final msg ----
    for (int idx = tid; idx < APM * AF; idx += 256) {
        int v = idx / AF, c = idx % AF;
        A[v * 300 + c] = x[(g * APM + v) * AF + c];
    }
    for (int ch = 0; ch < 4; ++ch) {
        if ((tc >> 4) == (ch & 1)) {
            int cc = tc & 15;
            #pragma unroll
            for (int i = 0; i < 5; ++i) {
                int r = tr * 5 + i;
                if (r < LEDGE) Sm[r * 16 + cc] = relu4(ch < 2 ? acc0[i] : acc1[i]);
            }
        }
        __syncthreads();
        for (int idx2 = tid; idx2 < APM * 16; idx2 += 256) {       // 320 items
            int v = idx2 >> 4, cc = idx2 & 15;
            f4 s = f4{};
            for (int j = noff[v]; j < noff[v + 1]; ++j)
                s += Sm[nlist[j] * 16 + cc];
            float* d = &A[v * 300 + AF + 4 * (ch * 16 + cc)];
            d[0] = s[0]; d[1] = s[1]; d[2] = s[2]; d[3] = s[3];
        }
        __syncthreads();
    }
    // out GEMM: rows v = tr*3+i (24 slots cover 20 rows), K=295
    const f4* WoT4 = (const f4*)&g_WoT[0];
    #pragma unroll
    for (int i = 0; i < 3; ++i) { acc0[i] = f4{}; acc1[i] = f4{}; }
    for (int kc = 0; kc < 19; ++kc) {
        int k0 = kc * 16;
        int klen = OUT_F - k0; if (klen > 16) klen = 16;
        for (int idx = tid; idx < klen * 64; idx += 256)
            S4[idx] = WoT4[(k0 + (idx >> 6)) * 64 + (idx & 63)];
        __syncthreads();
        for (int kl = 0; kl < klen; ++kl) {
            f4 b0 = S4[kl * 64 + tc];
            f4 b1 = S4[kl * 64 + 32 + tc];
            #pragma unroll
            for (int i = 0; i < 3; ++i) {
                float a = A[(tr * 3 + i) * 300 + k0 + kl];
                acc0[i] += a * b0;
                acc1[i] += a * b1;
            }
        }
        __syncthreads();
    }
    // bias + relu + per-column partial sums -> molecule mean
    {
        f4 bo0 = ((const f4*)bo)[tc];
        f4 bo1 = ((const f4*)bo)[32 + tc];
        f4 p0 = f4{}, p1 = f4{};
        #pragma unroll
        for (int i = 0; i < 3; ++i) {
            int v = tr * 3 + i;
            if (v < APM) {
                p0 += relu4(acc0[i] + bo0);
                p1 += relu4(acc1[i] + bo1);
            }
        }
        S4[tr * 32 + tc] = p0;            // P0[8][32]
        S4[256 + tr * 32 + tc] = p1;      // P1[8][32]
    }
    __syncthreads();
    if (tid < 64) {
        int c4 = tid;
        int base = (c4 < 32) ? c4 : (256 + (c4 - 32));
        f4 s = f4{};
        #pragma unroll
        for (int t = 0; t < 8; ++t) s += S4[base + t * 32];
        s *= (1.0f / APM);
        ((f4*)out)[(size_t)g * 64 + c4] = s;
    }
}

extern "C" void kernel_launch(void* const* d_in, const int* in_sizes, int n_in,
                              void* d_out, int out_size, void* d_ws, size_t ws_size,
                              hipStream_t stream) {
    const float* x  = (const float*)d_in[0];
    const float* bx = (const float*)d_in[1];
    const float* Wi = (const float*)d_in[2];
    const float* Wh = (const float*)d_in[3];
    const float* Wo = (const float*)d_in[4];
    const float* bo = (const float*)d_in[5];
    const int* esrc = (const int*)d_in[6];
    const int* edst = (const int*)d_in[7];
    // d_in[8..10] lg_src / lg_dst / graph_ids unused (rev-edge trick + contiguous molecules)
    float* out = (float*)d_out;

    int E  = in_sizes[1] / BF;
    int Eh = E / 2;
    int NM = out_size / HID;
    (void)d_ws; (void)ws_size; (void)n_in;   // d_ws deliberately unused

    const int TOTW = EDGE_F * HID + HID * HID + OUT_F * HID;  // 153,856
    k_prep<<<(TOTW + 255) / 256, 256, 0, stream>>>(Wi, Wh, Wo);
    k_mpnn<<<NM, 256, 0, stream>>>(x, bx, bo, esrc, edst, out, Eh);
}

// Round 7
// 2655.227 us; speedup vs baseline: 3.0711x; 3.0711x over previous
//
#include <hip/hip_runtime.h>

typedef float f32x4 __attribute__((ext_vector_type(4)));
typedef short bf16x8 __attribute__((ext_vector_type(8)));
typedef unsigned short u16;
typedef unsigned int u32;

#define HID 256
#define AF 39
#define BF 11
#define EDGE_F 50          // AF+BF
#define OUT_F 295          // AF+HID
#define APM 20
#define EPM 19
#define LEDGE 38
#define ROWS 40            // msg rows incl. pad (tiles read up to 48; overreads are contained)
#define MSTRIDE 512        // bytes per msg row (256 bf16)

// Fragment-packed weights (hi/lo bf16 split), ~655 KB module globals.
// slot = ((mt*KS + ks)*64 + lane)*8 + j ; h = mt*16+(lane&15) ; k = ks*32+((lane>>4)&3)*8+j
__device__ u16 g_whH[16*8*64*8],  g_whL[16*8*64*8];    // Wh  [256][256], KS=8
__device__ u16 g_wiH[16*2*64*8],  g_wiL[16*2*64*8];    // Wi  [256][50->64], KS=2
__device__ u16 g_woH[16*10*64*8], g_woL[16*10*64*8];   // Wo  [256][295->320], KS=10

__device__ __forceinline__ u16 f2bf(float f) {
    u32 u = __builtin_bit_cast(u32, f);
    u += 0x7FFF + ((u >> 16) & 1);            // RNE
    return (u16)(u >> 16);
}
__device__ __forceinline__ float bf2f(u16 h) {
    u32 u = ((u32)h) << 16;
    return __builtin_bit_cast(float, u);
}
__device__ __forceinline__ u32 pack2(float a, float b) {
    return (u32)f2bf(a) | ((u32)f2bf(b) << 16);
}
// swizzled byte address inside msg buffers ([ROWS][512B], XOR bank-swizzle)
__device__ __forceinline__ int msw(int r, int off) { return r * MSTRIDE + (off ^ ((r & 7) << 4)); }
// swizzled byte address inside cat buffers ([32][640B])
__device__ __forceinline__ int csw(int a, int off) { return a * 640 + (off ^ ((a & 7) << 4)); }

__global__ __launch_bounds__(256) void k_prep(const float* __restrict__ Wi,
                                              const float* __restrict__ Wh,
                                              const float* __restrict__ Wo) {
    int idx = blockIdx.x * 256 + threadIdx.x;
    if (idx >= 163840) return;
    float w; u16 *H, *L; int slot;
    if (idx < 65536) {                       // Wh
        slot = idx;
        int j = slot & 7, l = (slot >> 3) & 63, rest = slot >> 9;
        int ks = rest & 7, mt = rest >> 3;
        int h = mt * 16 + (l & 15), k = ks * 32 + ((l >> 4) & 3) * 8 + j;
        w = Wh[h * HID + k]; H = g_whH; L = g_whL;
    } else if (idx < 81920) {                // Wi
        slot = idx - 65536;
        int j = slot & 7, l = (slot >> 3) & 63, rest = slot >> 9;
        int ks = rest & 1, mt = rest >> 1;
        int h = mt * 16 + (l & 15), k = ks * 32 + ((l >> 4) & 3) * 8 + j;
        w = (k < EDGE_F) ? Wi[h * EDGE_F + k] : 0.f; H = g_wiH; L = g_wiL;
    } else {                                 // Wo
        slot = idx - 81920;
        int j = slot & 7, l = (slot >> 3) & 63, rest = slot >> 9;
        int ks = rest % 10, mt = rest / 10;
        int h = mt * 16 + (l & 15), k = ks * 32 + ((l >> 4) & 3) * 8 + j;
        w = (k < OUT_F) ? Wo[h * OUT_F + k] : 0.f; H = g_woH; L = g_woL;
    }
    u16 hi = f2bf(w);
    H[slot] = hi;
    L[slot] = f2bf(w - bf2f(hi));
}

struct SB_t {
    u16   MH[ROWS * 256];    // 20480 B : msg hi  | feats hi | catH[32][320] | h2 (w/ ML)
    u16   ML[ROWS * 256];    // 20480 B : msg lo  | feats lo | catL
    float NS[APM * 256];     // 20480 B : node sums fp32 | bo stash
    int srcloc[LEDGE], dstloc[LEDGE], noff[APM + 1], nlist[LEDGE], ncnt[APM];
};

__global__ __launch_bounds__(256) void k_mpnn(
        const float* __restrict__ x, const float* __restrict__ bx,
        const float* __restrict__ bo,
        const int* __restrict__ esrc, const int* __restrict__ edst,
        float* __restrict__ out, int Eh) {
    __shared__ __align__(16) SB_t sb;
    const int tid = threadIdx.x;
    const int gm  = blockIdx.x;
    const int w    = tid >> 6;        // wave 0..3  -> owns h in [w*64, w*64+64)
    const int lane = tid & 63;
    const int l15  = lane & 15;
    const int lb   = lane >> 4;       // 0..3
    char* MHc = (char*)sb.MH;
    char* MLc = (char*)sb.ML;

    // ---- topology ----
    if (tid < EPM) {
        int e = gm * EPM + tid;
        int s = esrc[e] - gm * APM;
        int d = edst[e] - gm * APM;
        sb.srcloc[tid] = s;        sb.dstloc[tid] = d;
        sb.srcloc[tid + EPM] = d;  sb.dstloc[tid + EPM] = s;
    }
    __syncthreads();
    if (tid == 0) {
        for (int v = 0; v < APM; ++v) sb.ncnt[v] = 0;
        for (int r = 0; r < LEDGE; ++r) sb.ncnt[sb.dstloc[r]]++;
        sb.noff[0] = 0;
        for (int v = 0; v < APM; ++v) sb.noff[v + 1] = sb.noff[v] + sb.ncnt[v];
        for (int v = 0; v < APM; ++v) sb.ncnt[v] = 0;
        for (int r = 0; r < LEDGE; ++r) {
            int v = sb.dstloc[r];
            sb.nlist[sb.noff[v] + sb.ncnt[v]++] = r;
        }
    }
    // ---- feats (hi/lo bf16) into MH/ML rows, k<64, zero-padded ----
    for (int it = tid; it < ROWS * 64; it += 256) {
        int r = it >> 6, k = it & 63;
        float v = 0.f;
        if (r < LEDGE && k < EDGE_F) {
            int ge = (r < EPM) ? gm * EPM + r : Eh + gm * EPM + (r - EPM);
            v = (k < AF) ? x[(gm * APM + sb.srcloc[r]) * AF + k] : bx[ge * BF + (k - AF)];
        }
        u16 hi = f2bf(v);
        *(u16*)(MHc + msw(r, 2 * k)) = hi;
        *(u16*)(MLc + msw(r, 2 * k)) = f2bf(v - bf2f(hi));
    }
    __syncthreads();

    // ---- iter0: MI[h][e] = Wi . feats^T  (bf16x3, fp32 acc), kept pre-relu in regs ----
    f32x4 MI[4][3];
    #pragma unroll
    for (int mt2 = 0; mt2 < 4; ++mt2)
        #pragma unroll
        for (int nt = 0; nt < 3; ++nt) MI[mt2][nt] = f32x4{};
    #pragma unroll
    for (int ks = 0; ks < 2; ++ks) {
        bf16x8 BH[3], BL[3];
        #pragma unroll
        for (int nt = 0; nt < 3; ++nt) {
            int a = msw(nt * 16 + l15, ks * 64 + lb * 16);
            BH[nt] = *(const bf16x8*)(MHc + a);
            BL[nt] = *(const bf16x8*)(MLc + a);
        }
        #pragma unroll
        for (int mt2 = 0; mt2 < 4; ++mt2) {
            int slot = (((w * 4 + mt2) * 2 + ks) * 64 + lane) * 8;
            bf16x8 AH = *(const bf16x8*)&g_wiH[slot];
            bf16x8 AL = *(const bf16x8*)&g_wiL[slot];
            #pragma unroll
            for (int nt = 0; nt < 3; ++nt) {
                MI[mt2][nt] = __builtin_amdgcn_mfma_f32_16x16x32_bf16(AH, BH[nt], MI[mt2][nt], 0, 0, 0);
                MI[mt2][nt] = __builtin_amdgcn_mfma_f32_16x16x32_bf16(AH, BL[nt], MI[mt2][nt], 0, 0, 0);
                MI[mt2][nt] = __builtin_amdgcn_mfma_f32_16x16x32_bf16(AL, BH[nt], MI[mt2][nt], 0, 0, 0);
            }
        }
    }
    __syncthreads();                       // feats reads done; msg writes may begin

    // msg0 = relu(MI) -> MH/ML
    #pragma unroll
    for (int mt2 = 0; mt2 < 4; ++mt2)
        #pragma unroll
        for (int nt = 0; nt < 3; ++nt) {
            int e = nt * 16 + l15;
            if (e < LEDGE) {
                int h0b = 2 * ((w * 4 + mt2) * 16 + lb * 4);
                f32x4 d = MI[mt2][nt];
                float r0 = fmaxf(d[0], 0.f), r1 = fmaxf(d[1], 0.f);
                float r2 = fmaxf(d[2], 0.f), r3 = fmaxf(d[3], 0.f);
                uint2 ph, pl;
                ph.x = pack2(r0, r1); ph.y = pack2(r2, r3);
                pl.x = pack2(r0 - bf2f(f2bf(r0)), r1 - bf2f(f2bf(r1)));
                pl.y = pack2(r2 - bf2f(f2bf(r2)), r3 - bf2f(f2bf(r3)));
                *(uint2*)(MHc + msw(e, h0b)) = ph;
                *(uint2*)(MLc + msw(e, h0b)) = pl;
            }
        }
    __syncthreads();

    // ---- 5 message-passing iterations ----
    for (int itr = 0; itr < 5; ++itr) {
        // ns[v] = sum of msg over in-edges (fp32 from hi+lo)
        for (int it = tid; it < APM * 32; it += 256) {
            int v = it >> 5, c8 = it & 31;
            float s0=0,s1=0,s2=0,s3=0,s4=0,s5=0,s6=0,s7=0;
            for (int j = sb.noff[v]; j < sb.noff[v + 1]; ++j) {
                int a = msw(sb.nlist[j], c8 * 16);
                uint4 h4 = *(const uint4*)(MHc + a);
                uint4 l4 = *(const uint4*)(MLc + a);
                s0 += bf2f((u16)(h4.x)) + bf2f((u16)(l4.x));
                s1 += bf2f((u16)(h4.x >> 16)) + bf2f((u16)(l4.x >> 16));
                s2 += bf2f((u16)(h4.y)) + bf2f((u16)(l4.y));
                s3 += bf2f((u16)(h4.y >> 16)) + bf2f((u16)(l4.y >> 16));
                s4 += bf2f((u16)(h4.z)) + bf2f((u16)(l4.z));
                s5 += bf2f((u16)(h4.z >> 16)) + bf2f((u16)(l4.z >> 16));
                s6 += bf2f((u16)(h4.w)) + bf2f((u16)(l4.w));
                s7 += bf2f((u16)(h4.w >> 16)) + bf2f((u16)(l4.w >> 16));
            }
            f32x4 o0 = {s0, s1, s2, s3}, o1 = {s4, s5, s6, s7};
            *(f32x4*)&sb.NS[v * 256 + c8 * 8]     = o0;
            *(f32x4*)&sb.NS[v * 256 + c8 * 8 + 4] = o1;
        }
        __syncthreads();
        // agg[e] = ns[src[e]] - msg[rev[e]], hi/lo, in place (pair-swap)
        for (int it = tid; it < EPM * 32; it += 256) {
            int p = it >> 5, c8 = it & 31;
            int rA = p, rB = p + EPM;
            int aA = msw(rA, c8 * 16), aB = msw(rB, c8 * 16);
            uint4 hA = *(const uint4*)(MHc + aA), lA = *(const uint4*)(MLc + aA);
            uint4 hB = *(const uint4*)(MHc + aB), lB = *(const uint4*)(MLc + aB);
            int sA = sb.srcloc[rA], sB = sb.srcloc[rB];
            f32x4 nA0 = *(const f32x4*)&sb.NS[sA * 256 + c8 * 8];
            f32x4 nA1 = *(const f32x4*)&sb.NS[sA * 256 + c8 * 8 + 4];
            f32x4 nB0 = *(const f32x4*)&sb.NS[sB * 256 + c8 * 8];
            f32x4 nB1 = *(const f32x4*)&sb.NS[sB * 256 + c8 * 8 + 4];
            float mA[8], mB[8], gA[8], gB[8];
            mA[0]=bf2f((u16)hA.x)+bf2f((u16)lA.x); mA[1]=bf2f((u16)(hA.x>>16))+bf2f((u16)(lA.x>>16));
            mA[2]=bf2f((u16)hA.y)+bf2f((u16)lA.y); mA[3]=bf2f((u16)(hA.y>>16))+bf2f((u16)(lA.y>>16));
            mA[4]=bf2f((u16)hA.z)+bf2f((u16)lA.z); mA[5]=bf2f((u16)(hA.z>>16))+bf2f((u16)(lA.z>>16));
            mA[6]=bf2f((u16)hA.w)+bf2f((u16)lA.w); mA[7]=bf2f((u16)(hA.w>>16))+bf2f((u16)(lA.w>>16));
            mB[0]=bf2f((u16)hB.x)+bf2f((u16)lB.x); mB[1]=bf2f((u16)(hB.x>>16))+bf2f((u16)(lB.x>>16));
            mB[2]=bf2f((u16)hB.y)+bf2f((u16)lB.y); mB[3]=bf2f((u16)(hB.y>>16))+bf2f((u16)(lB.y>>16));
            mB[4]=bf2f((u16)hB.z)+bf2f((u16)lB.z); mB[5]=bf2f((u16)(hB.z>>16))+bf2f((u16)(lB.z>>16));
            mB[6]=bf2f((u16)hB.w)+bf2f((u16)lB.w); mB[7]=bf2f((u16)(hB.w>>16))+bf2f((u16)(lB.w>>16));
            gA[0]=nA0[0]-mB[0]; gA[1]=nA0[1]-mB[1]; gA[2]=nA0[2]-mB[2]; gA[3]=nA0[3]-mB[3];
            gA[4]=nA1[0]-mB[4]; gA[5]=nA1[1]-mB[5]; gA[6]=nA1[2]-mB[6]; gA[7]=nA1[3]-mB[7];
            gB[0]=nB0[0]-mA[0]; gB[1]=nB0[1]-mA[1]; gB[2]=nB0[2]-mA[2]; gB[3]=nB0[3]-mA[3];
            gB[4]=nB1[0]-mA[4]; gB[5]=nB1[1]-mA[5]; gB[6]=nB1[2]-mA[6]; gB[7]=nB1[3]-mA[7];
            uint4 oh, ol;
            oh.x=pack2(gA[0],gA[1]); oh.y=pack2(gA[2],gA[3]); oh.z=pack2(gA[4],gA[5]); oh.w=pack2(gA[6],gA[7]);
            ol.x=pack2(gA[0]-bf2f(f2bf(gA[0])), gA[1]-bf2f(f2bf(gA[1])));
            ol.y=pack2(gA[2]-bf2f(f2bf(gA[2])), gA[3]-bf2f(f2bf(gA[3])));
            ol.z=pack2(gA[4]-bf2f(f2bf(gA[4])), gA[5]-bf2f(f2bf(gA[5])));
            ol.w=pack2(gA[6]-bf2f(f2bf(gA[6])), gA[7]-bf2f(f2bf(gA[7])));
            *(uint4*)(MHc + aA) = oh; *(uint4*)(MLc + aA) = ol;
            oh.x=pack2(gB[0],gB[1]); oh.y=pack2(gB[2],gB[3]); oh.z=pack2(gB[4],gB[5]); oh.w=pack2(gB[6],gB[7]);
            ol.x=pack2(gB[0]-bf2f(f2bf(gB[0])), gB[1]-bf2f(f2bf(gB[1])));
            ol.y=pack2(gB[2]-bf2f(f2bf(gB[2])), gB[3]-bf2f(f2bf(gB[3])));
            ol.z=pack2(gB[4]-bf2f(f2bf(gB[4])), gB[5]-bf2f(f2bf(gB[5])));
            ol.w=pack2(gB[6]-bf2f(f2bf(gB[6])), gB[7]-bf2f(f2bf(gB[7])));
            *(uint4*)(MHc + aB) = oh; *(uint4*)(MLc + aB) = ol;
        }
        __syncthreads();
        // GEMM: C = MI + Wh . agg^T  (bf16x3)
        f32x4 C[4][3];
        #pragma unroll
        for (int mt2 = 0; mt2 < 4; ++mt2)
            #pragma unroll
            for (int nt = 0; nt < 3; ++nt) C[mt2][nt] = MI[mt2][nt];
        #pragma unroll
        for (int ks = 0; ks < 8; ++ks) {
            bf16x8 BH[3], BL[3];
            #pragma unroll
            for (int nt = 0; nt < 3; ++nt) {
                int a = msw(nt * 16 + l15, ks * 64 + lb * 16);
                BH[nt] = *(const bf16x8*)(MHc + a);
                BL[nt] = *(const bf16x8*)(MLc + a);
            }
            #pragma unroll
            for (int mt2 = 0; mt2 < 4; ++mt2) {
                int slot = (((w * 4 + mt2) * 8 + ks) * 64 + lane) * 8;
                bf16x8 AH = *(const bf16x8*)&g_whH[slot];
                bf16x8 AL = *(const bf16x8*)&g_whL[slot];
                #pragma unroll
                for (int nt = 0; nt < 3; ++nt) {
                    C[mt2][nt] = __builtin_amdgcn_mfma_f32_16x16x32_bf16(AH, BH[nt], C[mt2][nt], 0, 0, 0);
                    C[mt2][nt] = __builtin_amdgcn_mfma_f32_16x16x32_bf16(AH, BL[nt], C[mt2][nt], 0, 0, 0);
                    C[mt2][nt] = __builtin_amdgcn_mfma_f32_16x16x32_bf16(AL, BH[nt], C[mt2][nt], 0, 0, 0);
                }
            }
        }
        __syncthreads();                   // all agg reads done before overwrite
        // msg = relu(C) -> MH/ML
        #pragma unroll
        for (int mt2 = 0; mt2 < 4; ++mt2)
            #pragma unroll
            for (int nt = 0; nt < 3; ++nt) {
                int e = nt * 16 + l15;
                if (e < LEDGE) {
                    int h0b = 2 * ((w * 4 + mt2) * 16 + lb * 4);
                    f32x4 d = C[mt2][nt];
                    float r0 = fmaxf(d[0], 0.f), r1 = fmaxf(d[1], 0.f);
                    float r2 = fmaxf(d[2], 0.f), r3 = fmaxf(d[3], 0.f);
                    uint2 ph, pl;
                    ph.x = pack2(r0, r1); ph.y = pack2(r2, r3);
                    pl.x = pack2(r0 - bf2f(f2bf(r0)), r1 - bf2f(f2bf(r1)));
                    pl.y = pack2(r2 - bf2f(f2bf(r2)), r3 - bf2f(f2bf(r3)));
                    *(uint2*)(MHc + msw(e, h0b)) = ph;
                    *(uint2*)(MLc + msw(e, h0b)) = pl;
                }
            }
        __syncthreads();
    }

    // ---- final ns ----
    for (int it = tid; it < APM * 32; it += 256) {
        int v = it >> 5, c8 = it & 31;
        float s0=0,s1=0,s2=0,s3=0,s4=0,s5=0,s6=0,s7=0;
        for (int j = sb.noff[v]; j < sb.noff[v + 1]; ++j) {
            int a = msw(sb.nlist[j], c8 * 16);
            uint4 h4 = *(const uint4*)(MHc + a);
            uint4 l4 = *(const uint4*)(MLc + a);
            s0 += bf2f((u16)(h4.x)) + bf2f((u16)(l4.x));
            s1 += bf2f((u16)(h4.x >> 16)) + bf2f((u16)(l4.x >> 16));
            s2 += bf2f((u16)(h4.y)) + bf2f((u16)(l4.y));
            s3 += bf2f((u16)(h4.y >> 16)) + bf2f((u16)(l4.y >> 16));
            s4 += bf2f((u16)(h4.z)) + bf2f((u16)(l4.z));
            s5 += bf2f((u16)(h4.z >> 16)) + bf2f((u16)(l4.z >> 16));
            s6 += bf2f((u16)(h4.w)) + bf2f((u16)(l4.w));
            s7 += bf2f((u16)(h4.w >> 16)) + bf2f((u16)(l4.w >> 16));
        }
        f32x4 o0 = {s0, s1, s2, s3}, o1 = {s4, s5, s6, s7};
        *(f32x4*)&sb.NS[v * 256 + c8 * 8]     = o0;
        *(f32x4*)&sb.NS[v * 256 + c8 * 8 + 4] = o1;
    }
    __syncthreads();
    // ---- cat[a][k] = [x | m], hi/lo bf16, k<320 (pad zero) into MH/ML region ----
    for (int it = tid; it < APM * 320; it += 256) {
        int a = it / 320, k = it - a * 320;
        float v = 0.f;
        if (k < AF) v = x[(gm * APM + a) * AF + k];
        else if (k < OUT_F) v = sb.NS[a * 256 + (k - AF)];
        u16 hi = f2bf(v);
        *(u16*)(MHc + csw(a, 2 * k)) = hi;
        *(u16*)(MLc + csw(a, 2 * k)) = f2bf(v - bf2f(hi));
    }
    __syncthreads();
    if (tid < HID) sb.NS[tid] = bo[tid];      // bo stash (NS dead; ordered by post-GEMM barrier)
    // ---- out GEMM: D2[h][a] = Wo . cat^T ----
    f32x4 C2[4][2];
    #pragma unroll
    for (int mt2 = 0; mt2 < 4; ++mt2) { C2[mt2][0] = f32x4{}; C2[mt2][1] = f32x4{}; }
    #pragma unroll
    for (int ks = 0; ks < 10; ++ks) {
        bf16x8 BH[2], BL[2];
        #pragma unroll
        for (int nt = 0; nt < 2; ++nt) {
            int a = csw(nt * 16 + l15, ks * 64 + lb * 16);
            BH[nt] = *(const bf16x8*)(MHc + a);
            BL[nt] = *(const bf16x8*)(MLc + a);
        }
        #pragma unroll
        for (int mt2 = 0; mt2 < 4; ++mt2) {
            int slot = (((w * 4 + mt2) * 10 + ks) * 64 + lane) * 8;
            bf16x8 AH = *(const bf16x8*)&g_woH[slot];
            bf16x8 AL = *(const bf16x8*)&g_woL[slot];
            #pragma unroll
            for (int nt = 0; nt < 2; ++nt) {
                C2[mt2][nt] = __builtin_amdgcn_mfma_f32_16x16x32_bf16(AH, BH[nt], C2[mt2][nt], 0, 0, 0);
                C2[mt2][nt] = __builtin_amdgcn_mfma_f32_16x16x32_bf16(AH, BL[nt], C2[mt2][nt], 0, 0, 0);
                C2[mt2][nt] = __builtin_amdgcn_mfma_f32_16x16x32_bf16(AL, BH[nt], C2[mt2][nt], 0, 0, 0);
            }
        }
    }
    __syncthreads();                          // cat reads done; h2 overlays region
    // ---- h = relu(D2 + bo) into h2[256][36] fp32; then mean over atoms ----
    float* h2 = (float*)sb.MH;
    #pragma unroll
    for (int mt2 = 0; mt2 < 4; ++mt2)
        #pragma unroll
        for (int nt = 0; nt < 2; ++nt) {
            int a = nt * 16 + l15;
            int h0 = (w * 4 + mt2) * 16 + lb * 4;
            f32x4 d = C2[mt2][nt];
            #pragma unroll
            for (int r = 0; r < 4; ++r)
                h2[(h0 + r) * 36 + a] = fmaxf(d[r] + sb.NS[h0 + r], 0.f);
        }
    __syncthreads();
    {
        const f32x4* row = (const f32x4*)&h2[tid * 36];
        f32x4 s4v = row[0] + row[1] + row[2] + row[3] + row[4];   // 20 atoms
        out[(size_t)gm * HID + tid] = (s4v[0] + s4v[1] + s4v[2] + s4v[3]) * (1.0f / APM);
    }
}

extern "C" void kernel_launch(void* const* d_in, const int* in_sizes, int n_in,
                              void* d_out, int out_size, void* d_ws, size_t ws_size,
                              hipStream_t stream) {
    const float* x  = (const float*)d_in[0];
    const float* bx = (const float*)d_in[1];
    const float* Wi = (const float*)d_in[2];
    const float* Wh = (const float*)d_in[3];
    const float* Wo = (const float*)d_in[4];
    const float* bo = (const float*)d_in[5];
    const int* esrc = (const int*)d_in[6];
    const int* edst = (const int*)d_in[7];
    float* out = (float*)d_out;

    int E  = in_sizes[1] / BF;
    int Eh = E / 2;
    int NM = out_size / HID;
    (void)d_ws; (void)ws_size; (void)n_in;

    k_prep<<<640, 256, 0, stream>>>(Wi, Wh, Wo);
    k_mpnn<<<NM, 256, 0, stream>>>(x, bx, bo, esrc, edst, out, Eh);
}

// Round 8
// 1348.690 us; speedup vs baseline: 6.0462x; 1.9687x over previous
//
#include <hip/hip_runtime.h>

typedef float f32x4 __attribute__((ext_vector_type(4)));
typedef _Float16 f16x8 __attribute__((ext_vector_type(8)));
typedef unsigned short u16;
typedef unsigned int u32;

#define HID 256
#define AF 39
#define BF 11
#define EDGE_F 50          // AF+BF
#define OUT_F 295          // AF+HID
#define APM 20
#define EPM 19
#define LEDGE 38

// fp16 fragment-packed weights (~311 KB module globals, rewritten every launch).
// slot = ((mt*KS + ks)*64 + lane)*8 + j ; h = mt*16+(lane&15) ; k = ks*32+((lane>>4)&3)*8+j
__device__ u16 g_whF[16*8*64*8];    // Wh [256][256],       KS=8
__device__ u16 g_wiF[16*2*64*8];    // Wi [256][50->64],    KS=2
__device__ u16 g_woF[16*10*64*8];   // Wo [256][295->320],  KS=10

__device__ __forceinline__ u16 f2h(float f) {
    _Float16 h = (_Float16)f;                  // RNE
    return __builtin_bit_cast(u16, h);
}
// swizzled byte offsets (XOR bank-swizzle per G4)
__device__ __forceinline__ int msw(int r, int off) { return r * 512 + (off ^ ((r & 7) << 4)); }
__device__ __forceinline__ int fsw(int r, int off) { return r * 128 + (off ^ ((r & 7) << 4)); }
__device__ __forceinline__ int csw(int r, int off) { return r * 640 + (off ^ ((r & 7) << 4)); }

__global__ __launch_bounds__(256) void k_prep(const float* __restrict__ Wi,
                                              const float* __restrict__ Wh,
                                              const float* __restrict__ Wo) {
    int idx = blockIdx.x * 256 + threadIdx.x;
    if (idx >= 163840) return;
    float w; u16* D; int slot;
    if (idx < 65536) {                       // Wh
        slot = idx;
        int j = slot & 7, l = (slot >> 3) & 63, rest = slot >> 9;
        int ks = rest & 7, mt = rest >> 3;
        int h = mt * 16 + (l & 15), k = ks * 32 + ((l >> 4) & 3) * 8 + j;
        w = Wh[h * HID + k]; D = g_whF;
    } else if (idx < 81920) {                // Wi
        slot = idx - 65536;
        int j = slot & 7, l = (slot >> 3) & 63, rest = slot >> 9;
        int ks = rest & 1, mt = rest >> 1;
        int h = mt * 16 + (l & 15), k = ks * 32 + ((l >> 4) & 3) * 8 + j;
        w = (k < EDGE_F) ? Wi[h * EDGE_F + k] : 0.f; D = g_wiF;
    } else {                                 // Wo
        slot = idx - 81920;
        int j = slot & 7, l = (slot >> 3) & 63, rest = slot >> 9;
        int ks = rest % 10, mt = rest / 10;
        int h = mt * 16 + (l & 15), k = ks * 32 + ((l >> 4) & 3) * 8 + j;
        w = (k < OUT_F) ? Wo[h * OUT_F + k] : 0.f; D = g_woF;
    }
    D[slot] = f2h(w);
}

// LDS 36.5 KB -> 4 blocks/CU; VGPR target <=128 via __launch_bounds__(256,4).
struct SB_t {
    u16 MF[40 * 256];     // 20480 B: msg/agg fp16 | cat[32][640B] overlay in out phase
    u16 FE[40 * 64];      //  5120 B: feats fp16 (B-frag overreads land in NSF: cols>=38, discarded)
    u16 NSF[APM * 256];   // 10240 B: node-sum fp16
    int srcloc[LEDGE], dstloc[LEDGE], noff[APM + 1], nlist[LEDGE], ncnt[APM];
};

__global__ __launch_bounds__(256, 4) void k_mpnn(
        const float* __restrict__ x, const float* __restrict__ bx,
        const float* __restrict__ bo,
        const int* __restrict__ esrc, const int* __restrict__ edst,
        float* __restrict__ out, int Eh) {
    __shared__ __align__(16) SB_t sb;
    const int tid = threadIdx.x;
    const int gm  = blockIdx.x;
    const int w    = tid >> 6;        // wave 0..3 -> h in [w*64, w*64+64)
    const int lane = tid & 63;
    const int l15  = lane & 15;
    const int lb   = lane >> 4;       // 0..3
    char* MFc = (char*)sb.MF;
    char* FEc = (char*)sb.FE;
    char* NSc = (char*)sb.NSF;

    // ---- topology ----
    if (tid < EPM) {
        int e = gm * EPM + tid;
        int s = esrc[e] - gm * APM;
        int d = edst[e] - gm * APM;
        sb.srcloc[tid] = s;        sb.dstloc[tid] = d;
        sb.srcloc[tid + EPM] = d;  sb.dstloc[tid + EPM] = s;
    }
    __syncthreads();
    if (tid == 0) {
        for (int v = 0; v < APM; ++v) sb.ncnt[v] = 0;
        for (int r = 0; r < LEDGE; ++r) sb.ncnt[sb.dstloc[r]]++;
        sb.noff[0] = 0;
        for (int v = 0; v < APM; ++v) sb.noff[v + 1] = sb.noff[v] + sb.ncnt[v];
        for (int v = 0; v < APM; ++v) sb.ncnt[v] = 0;
        for (int r = 0; r < LEDGE; ++r) {
            int v = sb.dstloc[r];
            sb.nlist[sb.noff[v] + sb.ncnt[v]++] = r;
        }
    }
    // ---- feats fp16 [40 rows][64 k], zero-padded ----
    for (int it = tid; it < 40 * 64; it += 256) {
        int r = it >> 6, k = it & 63;
        float v = 0.f;
        if (r < LEDGE && k < EDGE_F) {
            int ge = (r < EPM) ? gm * EPM + r : Eh + gm * EPM + (r - EPM);
            v = (k < AF) ? x[(gm * APM + sb.srcloc[r]) * AF + k] : bx[ge * BF + (k - AF)];
        }
        *(u16*)(FEc + fsw(r, 2 * k)) = f2h(v);
    }
    __syncthreads();

    // per-iteration GEMM + relu-write (ITER0: Wi-part only; else Wi + Wh on agg in MF)
    const f16x8* whF = (const f16x8*)&g_whF[0];
    const f16x8* wiF = (const f16x8*)&g_wiF[0];

    for (int itr = 0; itr <= 5; ++itr) {
        if (itr > 0) {
            // ns[v] = sum of incoming msg (fp32 accum) -> NSF fp16
            for (int it = tid; it < APM * 32; it += 256) {
                int v = it >> 5, c8 = it & 31;
                float s[8] = {};
                for (int j = sb.noff[v]; j < sb.noff[v + 1]; ++j) {
                    f16x8 m = *(const f16x8*)(MFc + msw(sb.nlist[j], c8 * 16));
                    #pragma unroll
                    for (int q = 0; q < 8; ++q) s[q] += (float)m[q];
                }
                f16x8 o;
                #pragma unroll
                for (int q = 0; q < 8; ++q) o[q] = (_Float16)s[q];
                *(f16x8*)(NSc + msw(v, c8 * 16)) = o;
            }
            __syncthreads();
            // agg[e] = ns[src(e)] - msg[rev(e)], pairwise in place (race-free)
            for (int it = tid; it < EPM * 32; it += 256) {
                int p = it >> 5, c8 = it & 31;
                int rA = p, rB = p + EPM;
                int aA = msw(rA, c8 * 16), aB = msw(rB, c8 * 16);
                f16x8 mA = *(const f16x8*)(MFc + aA);
                f16x8 mB = *(const f16x8*)(MFc + aB);
                f16x8 nA = *(const f16x8*)(NSc + msw(sb.srcloc[rA], c8 * 16));
                f16x8 nB = *(const f16x8*)(NSc + msw(sb.srcloc[rB], c8 * 16));
                *(f16x8*)(MFc + aA) = nA - mB;
                *(f16x8*)(MFc + aB) = nB - mA;
            }
            __syncthreads();
        }
        // GEMM: C = Wi.featsT (+ Wh.aggT)
        f32x4 C[4][3];
        #pragma unroll
        for (int mt2 = 0; mt2 < 4; ++mt2)
            #pragma unroll
            for (int nt = 0; nt < 3; ++nt) C[mt2][nt] = f32x4{};
        #pragma unroll
        for (int ks = 0; ks < 2; ++ks) {
            f16x8 Bf[3];
            #pragma unroll
            for (int nt = 0; nt < 3; ++nt)
                Bf[nt] = *(const f16x8*)(FEc + fsw(nt * 16 + l15, ks * 64 + lb * 16));
            #pragma unroll
            for (int mt2 = 0; mt2 < 4; ++mt2) {
                f16x8 A = wiF[((w * 4 + mt2) * 2 + ks) * 64 + lane];
                #pragma unroll
                for (int nt = 0; nt < 3; ++nt)
                    C[mt2][nt] = __builtin_amdgcn_mfma_f32_16x16x32_f16(A, Bf[nt], C[mt2][nt], 0, 0, 0);
            }
        }
        if (itr > 0) {
            #pragma unroll
            for (int ks = 0; ks < 8; ++ks) {
                f16x8 Bf[3];
                #pragma unroll
                for (int nt = 0; nt < 3; ++nt)
                    Bf[nt] = *(const f16x8*)(MFc + msw(nt * 16 + l15, ks * 64 + lb * 16));
                #pragma unroll
                for (int mt2 = 0; mt2 < 4; ++mt2) {
                    f16x8 A = whF[((w * 4 + mt2) * 8 + ks) * 64 + lane];
                    #pragma unroll
                    for (int nt = 0; nt < 3; ++nt)
                        C[mt2][nt] = __builtin_amdgcn_mfma_f32_16x16x32_f16(A, Bf[nt], C[mt2][nt], 0, 0, 0);
                }
            }
        }
        __syncthreads();                 // all MF/FE reads done before msg overwrite
        // msg = relu(C) -> MF fp16
        #pragma unroll
        for (int mt2 = 0; mt2 < 4; ++mt2)
            #pragma unroll
            for (int nt = 0; nt < 3; ++nt) {
                int e = nt * 16 + l15;
                if (e < LEDGE) {
                    int h0b = 2 * ((w * 4 + mt2) * 16 + lb * 4);
                    f32x4 d = C[mt2][nt];
                    u32 lo = (u32)f2h(fmaxf(d[0], 0.f)) | ((u32)f2h(fmaxf(d[1], 0.f)) << 16);
                    u32 hi = (u32)f2h(fmaxf(d[2], 0.f)) | ((u32)f2h(fmaxf(d[3], 0.f)) << 16);
                    uint2 pk; pk.x = lo; pk.y = hi;
                    *(uint2*)(MFc + msw(e, h0b)) = pk;
                }
            }
        __syncthreads();
    }

    // ---- final ns -> NSF ----
    for (int it = tid; it < APM * 32; it += 256) {
        int v = it >> 5, c8 = it & 31;
        float s[8] = {};
        for (int j = sb.noff[v]; j < sb.noff[v + 1]; ++j) {
            f16x8 m = *(const f16x8*)(MFc + msw(sb.nlist[j], c8 * 16));
            #pragma unroll
            for (int q = 0; q < 8; ++q) s[q] += (float)m[q];
        }
        f16x8 o;
        #pragma unroll
        for (int q = 0; q < 8; ++q) o[q] = (_Float16)s[q];
        *(f16x8*)(NSc + msw(v, c8 * 16)) = o;
    }
    __syncthreads();
    // ---- cat[a][k<320] = [x | m] fp16 into MF region (msg dead) ----
    for (int it = tid; it < APM * 320; it += 256) {
        int a = it / 320, k = it - a * 320;
        float v = 0.f;
        if (k < AF) v = x[(gm * APM + a) * AF + k];
        else if (k < OUT_F) v = (float)(*(const _Float16*)(NSc + msw(a, 2 * (k - AF))));
        *(u16*)(MFc + csw(a, 2 * k)) = f2h(v);
    }
    __syncthreads();
    // ---- out GEMM: D2[h][a] = Wo . catT ----
    const f16x8* woF = (const f16x8*)&g_woF[0];
    f32x4 C2[4][2];
    #pragma unroll
    for (int mt2 = 0; mt2 < 4; ++mt2) { C2[mt2][0] = f32x4{}; C2[mt2][1] = f32x4{}; }
    #pragma unroll
    for (int ks = 0; ks < 10; ++ks) {
        f16x8 Bf[2];
        #pragma unroll
        for (int nt = 0; nt < 2; ++nt)
            Bf[nt] = *(const f16x8*)(MFc + csw(nt * 16 + l15, ks * 64 + lb * 16));
        #pragma unroll
        for (int mt2 = 0; mt2 < 4; ++mt2) {
            f16x8 A = woF[((w * 4 + mt2) * 10 + ks) * 64 + lane];
            #pragma unroll
            for (int nt = 0; nt < 2; ++nt)
                C2[mt2][nt] = __builtin_amdgcn_mfma_f32_16x16x32_f16(A, Bf[nt], C2[mt2][nt], 0, 0, 0);
        }
    }
    // ---- h = relu(D2+bo); molecule mean via 16-lane shfl reduction (no LDS) ----
    #pragma unroll
    for (int mt2 = 0; mt2 < 4; ++mt2)
        #pragma unroll
        for (int r = 0; r < 4; ++r) {
            int h = (w * 4 + mt2) * 16 + lb * 4 + r;
            float bov = bo[h];
            float s = fmaxf(C2[mt2][0][r] + bov, 0.f);                       // a = l15 (0..15)
            if (l15 < 4) s += fmaxf(C2[mt2][1][r] + bov, 0.f);               // a = 16 + l15
            s += __shfl_xor(s, 1); s += __shfl_xor(s, 2);
            s += __shfl_xor(s, 4); s += __shfl_xor(s, 8);
            if (l15 == 0) out[(size_t)gm * HID + h] = s * (1.0f / APM);
        }
}

extern "C" void kernel_launch(void* const* d_in, const int* in_sizes, int n_in,
                              void* d_out, int out_size, void* d_ws, size_t ws_size,
                              hipStream_t stream) {
    const float* x  = (const float*)d_in[0];
    const float* bx = (const float*)d_in[1];
    const float* Wi = (const float*)d_in[2];
    const float* Wh = (const float*)d_in[3];
    const float* Wo = (const float*)d_in[4];
    const float* bo = (const float*)d_in[5];
    const int* esrc = (const int*)d_in[6];
    const int* edst = (const int*)d_in[7];
    float* out = (float*)d_out;

    int E  = in_sizes[1] / BF;
    int Eh = E / 2;
    int NM = out_size / HID;
    (void)d_ws; (void)ws_size; (void)n_in;

    k_prep<<<640, 256, 0, stream>>>(Wi, Wh, Wo);
    k_mpnn<<<NM, 256, 0, stream>>>(x, bx, bo, esrc, edst, out, Eh);
}

// Round 9
// 783.742 us; speedup vs baseline: 10.4046x; 1.7208x over previous
//
#include <hip/hip_runtime.h>

typedef float f32x4 __attribute__((ext_vector_type(4)));
typedef _Float16 f16x8 __attribute__((ext_vector_type(8)));
typedef unsigned short u16;
typedef unsigned int u32;

#define HID 256
#define AF 39
#define BF 11
#define EDGE_F 50          // AF+BF
#define OUT_F 295          // AF+HID
#define APM 20
#define EPM 19
#define LEDGE 38

// fp16 fragment-packed weights (~311 KB module globals, rewritten every launch).
// slot = ((mt*KS + ks)*64 + lane)*8 + j ; h = mt*16+(lane&15) ; k = ks*32+((lane>>4)&3)*8+j
__device__ u16 g_whF[16*8*64*8];    // Wh [256][256],       KS=8
__device__ u16 g_wiF[16*2*64*8];    // Wi [256][50->64],    KS=2
__device__ u16 g_woF[16*10*64*8];   // Wo [256][295->320],  KS=10

__device__ __forceinline__ u16 f2h(float f) {
    _Float16 h = (_Float16)f;                  // RNE
    return __builtin_bit_cast(u16, h);
}
// swizzled byte offsets (XOR bank-swizzle per G4)
__device__ __forceinline__ int msw(int r, int off) { return r * 512 + (off ^ ((r & 7) << 4)); }
__device__ __forceinline__ int fsw(int r, int off) { return r * 128 + (off ^ ((r & 7) << 4)); }
__device__ __forceinline__ int csw(int r, int off) { return r * 640 + (off ^ ((r & 7) << 4)); }

__global__ __launch_bounds__(256) void k_prep(const float* __restrict__ Wi,
                                              const float* __restrict__ Wh,
                                              const float* __restrict__ Wo) {
    int idx = blockIdx.x * 256 + threadIdx.x;
    if (idx >= 163840) return;
    float w; u16* D; int slot;
    if (idx < 65536) {                       // Wh
        slot = idx;
        int j = slot & 7, l = (slot >> 3) & 63, rest = slot >> 9;
        int ks = rest & 7, mt = rest >> 3;
        int h = mt * 16 + (l & 15), k = ks * 32 + ((l >> 4) & 3) * 8 + j;
        w = Wh[h * HID + k]; D = g_whF;
    } else if (idx < 81920) {                // Wi
        slot = idx - 65536;
        int j = slot & 7, l = (slot >> 3) & 63, rest = slot >> 9;
        int ks = rest & 1, mt = rest >> 1;
        int h = mt * 16 + (l & 15), k = ks * 32 + ((l >> 4) & 3) * 8 + j;
        w = (k < EDGE_F) ? Wi[h * EDGE_F + k] : 0.f; D = g_wiF;
    } else {                                 // Wo
        slot = idx - 81920;
        int j = slot & 7, l = (slot >> 3) & 63, rest = slot >> 9;
        int ks = rest % 10, mt = rest / 10;
        int h = mt * 16 + (l & 15), k = ks * 32 + ((l >> 4) & 3) * 8 + j;
        w = (k < OUT_F) ? Wo[h * OUT_F + k] : 0.f; D = g_woF;
    }
    D[slot] = f2h(w);
}

// Named-member fragment structs (rule #20: no runtime-indexed arrays -> no scratch)
struct frag4 { f16x8 v0, v1, v2, v3; };
struct frag3 { f16x8 b0, b1, b2; };
struct frag2 { f16x8 b0, b1; };

// A-fragment stream for iteration GEMM: steps 0..1 = Wi, 2..9 = Wh
__device__ __forceinline__ frag4 loadA_ih(int step, int w, int lane) {
    frag4 r;
    if (step < 2) {
        const f16x8* p = (const f16x8*)&g_wiF[0];
        r.v0 = p[((w * 4 + 0) * 2 + step) * 64 + lane];
        r.v1 = p[((w * 4 + 1) * 2 + step) * 64 + lane];
        r.v2 = p[((w * 4 + 2) * 2 + step) * 64 + lane];
        r.v3 = p[((w * 4 + 3) * 2 + step) * 64 + lane];
    } else {
        int ks = step - 2;
        const f16x8* p = (const f16x8*)&g_whF[0];
        r.v0 = p[((w * 4 + 0) * 8 + ks) * 64 + lane];
        r.v1 = p[((w * 4 + 1) * 8 + ks) * 64 + lane];
        r.v2 = p[((w * 4 + 2) * 8 + ks) * 64 + lane];
        r.v3 = p[((w * 4 + 3) * 8 + ks) * 64 + lane];
    }
    return r;
}
__device__ __forceinline__ frag4 loadA_o(int step, int w, int lane) {
    frag4 r;
    const f16x8* p = (const f16x8*)&g_woF[0];
    r.v0 = p[((w * 4 + 0) * 10 + step) * 64 + lane];
    r.v1 = p[((w * 4 + 1) * 10 + step) * 64 + lane];
    r.v2 = p[((w * 4 + 2) * 10 + step) * 64 + lane];
    r.v3 = p[((w * 4 + 3) * 10 + step) * 64 + lane];
    return r;
}
// B fragments: steps 0..1 read feats (FE), steps 2..9 read agg/msg (MF)
__device__ __forceinline__ frag3 loadB_ih(const char* MFc, const char* FEc,
                                          int step, int l15, int lb) {
    frag3 r;
    if (step < 2) {
        r.b0 = *(const f16x8*)(FEc + fsw( 0 + l15, step * 64 + lb * 16));
        r.b1 = *(const f16x8*)(FEc + fsw(16 + l15, step * 64 + lb * 16));
        r.b2 = *(const f16x8*)(FEc + fsw(32 + l15, step * 64 + lb * 16));
    } else {
        int o = (step - 2) * 64 + lb * 16;
        r.b0 = *(const f16x8*)(MFc + msw( 0 + l15, o));
        r.b1 = *(const f16x8*)(MFc + msw(16 + l15, o));
        r.b2 = *(const f16x8*)(MFc + msw(32 + l15, o));
    }
    return r;
}
__device__ __forceinline__ frag2 loadB_o(const char* MFc, int step, int l15, int lb) {
    frag2 r;
    int o = step * 64 + lb * 16;
    r.b0 = *(const f16x8*)(MFc + csw( 0 + l15, o));
    r.b1 = *(const f16x8*)(MFc + csw(16 + l15, o));
    return r;
}

#define MF16(A_, B_, C_) __builtin_amdgcn_mfma_f32_16x16x32_f16(A_, B_, C_, 0, 0, 0)
#define GSTEP3(AA, BB) do { \
    C[0][0]=MF16(AA.v0,BB.b0,C[0][0]); C[0][1]=MF16(AA.v0,BB.b1,C[0][1]); C[0][2]=MF16(AA.v0,BB.b2,C[0][2]); \
    C[1][0]=MF16(AA.v1,BB.b0,C[1][0]); C[1][1]=MF16(AA.v1,BB.b1,C[1][1]); C[1][2]=MF16(AA.v1,BB.b2,C[1][2]); \
    C[2][0]=MF16(AA.v2,BB.b0,C[2][0]); C[2][1]=MF16(AA.v2,BB.b1,C[2][1]); C[2][2]=MF16(AA.v2,BB.b2,C[2][2]); \
    C[3][0]=MF16(AA.v3,BB.b0,C[3][0]); C[3][1]=MF16(AA.v3,BB.b1,C[3][1]); C[3][2]=MF16(AA.v3,BB.b2,C[3][2]); \
} while (0)
#define GSTEP2(AA, BB) do { \
    C2[0][0]=MF16(AA.v0,BB.b0,C2[0][0]); C2[0][1]=MF16(AA.v0,BB.b1,C2[0][1]); \
    C2[1][0]=MF16(AA.v1,BB.b0,C2[1][0]); C2[1][1]=MF16(AA.v1,BB.b1,C2[1][1]); \
    C2[2][0]=MF16(AA.v2,BB.b0,C2[2][0]); C2[2][1]=MF16(AA.v2,BB.b1,C2[2][1]); \
    C2[3][0]=MF16(AA.v3,BB.b0,C2[3][0]); C2[3][1]=MF16(AA.v3,BB.b1,C2[3][1]); \
} while (0)

// LDS 36.5 KB -> 4 blocks/CU; VGPR target <=128 via __launch_bounds__(256,4).
struct SB_t {
    u16 MF[40 * 256];     // 20480 B: msg/agg fp16 | cat[32][640B] overlay in out phase
    u16 FE[40 * 64];      //  5120 B: feats fp16 (B-frag row-overreads land in NSF, discarded)
    u16 NSF[APM * 256];   // 10240 B: node-sum fp16
    int srcloc[LEDGE], dstloc[LEDGE], noff[APM + 1], nlist[LEDGE], ncnt[APM];
};

__global__ __launch_bounds__(256, 4) void k_mpnn(
        const float* __restrict__ x, const float* __restrict__ bx,
        const float* __restrict__ bo,
        const int* __restrict__ esrc, const int* __restrict__ edst,
        float* __restrict__ out, int Eh) {
    __shared__ __align__(16) SB_t sb;
    const int tid = threadIdx.x;
    const int gm  = blockIdx.x;
    const int w    = tid >> 6;        // wave 0..3 -> h in [w*64, w*64+64)
    const int lane = tid & 63;
    const int l15  = lane & 15;
    const int lb   = lane >> 4;       // 0..3
    char* MFc = (char*)sb.MF;
    char* FEc = (char*)sb.FE;
    char* NSc = (char*)sb.NSF;

    // ---- topology ----
    if (tid < EPM) {
        int e = gm * EPM + tid;
        int s = esrc[e] - gm * APM;
        int d = edst[e] - gm * APM;
        sb.srcloc[tid] = s;        sb.dstloc[tid] = d;
        sb.srcloc[tid + EPM] = d;  sb.dstloc[tid + EPM] = s;
    }
    __syncthreads();
    if (tid == 0) {
        for (int v = 0; v < APM; ++v) sb.ncnt[v] = 0;
        for (int r = 0; r < LEDGE; ++r) sb.ncnt[sb.dstloc[r]]++;
        sb.noff[0] = 0;
        for (int v = 0; v < APM; ++v) sb.noff[v + 1] = sb.noff[v] + sb.ncnt[v];
        for (int v = 0; v < APM; ++v) sb.ncnt[v] = 0;
        for (int r = 0; r < LEDGE; ++r) {
            int v = sb.dstloc[r];
            sb.nlist[sb.noff[v] + sb.ncnt[v]++] = r;
        }
    }
    // ---- feats fp16 [40 rows][64 k], zero-padded (non-temporal input reads) ----
    for (int it = tid; it < 40 * 64; it += 256) {
        int r = it >> 6, k = it & 63;
        float v = 0.f;
        if (r < LEDGE && k < EDGE_F) {
            int ge = (r < EPM) ? gm * EPM + r : Eh + gm * EPM + (r - EPM);
            v = (k < AF) ? __builtin_nontemporal_load(&x[(gm * APM + sb.srcloc[r]) * AF + k])
                         : __builtin_nontemporal_load(&bx[ge * BF + (k - AF)]);
        }
        *(u16*)(FEc + fsw(r, 2 * k)) = f2h(v);
    }
    __syncthreads();

    for (int itr = 0; itr <= 5; ++itr) {
        if (itr > 0) {
            // ns[v] = sum of incoming msg (fp32 accum) -> NSF fp16
            for (int it = tid; it < APM * 32; it += 256) {
                int v = it >> 5, c8 = it & 31;
                float s[8] = {};
                for (int j = sb.noff[v]; j < sb.noff[v + 1]; ++j) {
                    f16x8 m = *(const f16x8*)(MFc + msw(sb.nlist[j], c8 * 16));
                    #pragma unroll
                    for (int q = 0; q < 8; ++q) s[q] += (float)m[q];
                }
                f16x8 o;
                #pragma unroll
                for (int q = 0; q < 8; ++q) o[q] = (_Float16)s[q];
                *(f16x8*)(NSc + msw(v, c8 * 16)) = o;
            }
            __syncthreads();
            // agg[e] = ns[src(e)] - msg[rev(e)], pairwise in place (race-free)
            for (int it = tid; it < EPM * 32; it += 256) {
                int p = it >> 5, c8 = it & 31;
                int rA = p, rB = p + EPM;
                int aA = msw(rA, c8 * 16), aB = msw(rB, c8 * 16);
                f16x8 mA = *(const f16x8*)(MFc + aA);
                f16x8 mB = *(const f16x8*)(MFc + aB);
                f16x8 nA = *(const f16x8*)(NSc + msw(sb.srcloc[rA], c8 * 16));
                f16x8 nB = *(const f16x8*)(NSc + msw(sb.srcloc[rB], c8 * 16));
                *(f16x8*)(MFc + aA) = nA - mB;
                *(f16x8*)(MFc + aB) = nB - mA;
            }
            __syncthreads();
        }
        // ---- GEMM: C = Wi.featsT (+ Wh.aggT), depth-2 pipelined weight stream ----
        f32x4 C[4][3];
        #pragma unroll
        for (int mt2 = 0; mt2 < 4; ++mt2)
            #pragma unroll
            for (int nt = 0; nt < 3; ++nt) C[mt2][nt] = f32x4{};
        const int nsteps = (itr > 0) ? 10 : 2;     // always even
        frag4 Aa = loadA_ih(0, w, lane);
        frag4 Ab = loadA_ih(1, w, lane);
        __builtin_amdgcn_s_setprio(1);
        #pragma unroll 1
        for (int s2 = 0; s2 < nsteps; s2 += 2) {
            frag3 B0 = loadB_ih(MFc, FEc, s2, l15, lb);
            GSTEP3(Aa, B0);
            if (s2 + 2 < nsteps) Aa = loadA_ih(s2 + 2, w, lane);
            frag3 B1 = loadB_ih(MFc, FEc, s2 + 1, l15, lb);
            GSTEP3(Ab, B1);
            if (s2 + 3 < nsteps) Ab = loadA_ih(s2 + 3, w, lane);
        }
        __builtin_amdgcn_s_setprio(0);
        __syncthreads();                 // all MF/FE reads done before msg overwrite
        // msg = relu(C) -> MF fp16
        #pragma unroll
        for (int mt2 = 0; mt2 < 4; ++mt2)
            #pragma unroll
            for (int nt = 0; nt < 3; ++nt) {
                int e = nt * 16 + l15;
                if (e < LEDGE) {
                    int h0b = 2 * ((w * 4 + mt2) * 16 + lb * 4);
                    f32x4 d = C[mt2][nt];
                    u32 lo = (u32)f2h(fmaxf(d[0], 0.f)) | ((u32)f2h(fmaxf(d[1], 0.f)) << 16);
                    u32 hi = (u32)f2h(fmaxf(d[2], 0.f)) | ((u32)f2h(fmaxf(d[3], 0.f)) << 16);
                    uint2 pk; pk.x = lo; pk.y = hi;
                    *(uint2*)(MFc + msw(e, h0b)) = pk;
                }
            }
        __syncthreads();
    }

    // ---- final ns -> NSF ----
    for (int it = tid; it < APM * 32; it += 256) {
        int v = it >> 5, c8 = it & 31;
        float s[8] = {};
        for (int j = sb.noff[v]; j < sb.noff[v + 1]; ++j) {
            f16x8 m = *(const f16x8*)(MFc + msw(sb.nlist[j], c8 * 16));
            #pragma unroll
            for (int q = 0; q < 8; ++q) s[q] += (float)m[q];
        }
        f16x8 o;
        #pragma unroll
        for (int q = 0; q < 8; ++q) o[q] = (_Float16)s[q];
        *(f16x8*)(NSc + msw(v, c8 * 16)) = o;
    }
    __syncthreads();
    // ---- cat[a][k<320] = [x | m] fp16 into MF region (msg dead) ----
    for (int it = tid; it < APM * 320; it += 256) {
        int a = it / 320, k = it - a * 320;
        float v = 0.f;
        if (k < AF) v = __builtin_nontemporal_load(&x[(gm * APM + a) * AF + k]);
        else if (k < OUT_F) v = (float)(*(const _Float16*)(NSc + msw(a, 2 * (k - AF))));
        *(u16*)(MFc + csw(a, 2 * k)) = f2h(v);
    }
    __syncthreads();
    // ---- out GEMM: D2[h][a] = Wo . catT, depth-2 pipelined ----
    f32x4 C2[4][2];
    #pragma unroll
    for (int mt2 = 0; mt2 < 4; ++mt2) { C2[mt2][0] = f32x4{}; C2[mt2][1] = f32x4{}; }
    {
        frag4 Aa = loadA_o(0, w, lane);
        frag4 Ab = loadA_o(1, w, lane);
        __builtin_amdgcn_s_setprio(1);
        #pragma unroll 1
        for (int s2 = 0; s2 < 10; s2 += 2) {
            frag2 B0 = loadB_o(MFc, s2, l15, lb);
            GSTEP2(Aa, B0);
            if (s2 + 2 < 10) Aa = loadA_o(s2 + 2, w, lane);
            frag2 B1 = loadB_o(MFc, s2 + 1, l15, lb);
            GSTEP2(Ab, B1);
            if (s2 + 3 < 10) Ab = loadA_o(s2 + 3, w, lane);
        }
        __builtin_amdgcn_s_setprio(0);
    }
    // ---- h = relu(D2+bo); molecule mean via 16-lane shfl reduction (no LDS) ----
    #pragma unroll
    for (int mt2 = 0; mt2 < 4; ++mt2)
        #pragma unroll
        for (int r = 0; r < 4; ++r) {
            int h = (w * 4 + mt2) * 16 + lb * 4 + r;
            float bov = bo[h];
            float s = fmaxf(C2[mt2][0][r] + bov, 0.f);                       // a = l15
            if (l15 < 4) s += fmaxf(C2[mt2][1][r] + bov, 0.f);               // a = 16 + l15
            s += __shfl_xor(s, 1); s += __shfl_xor(s, 2);
            s += __shfl_xor(s, 4); s += __shfl_xor(s, 8);
            if (l15 == 0)
                __builtin_nontemporal_store(s * (1.0f / APM), &out[(size_t)gm * HID + h]);
        }
}

extern "C" void kernel_launch(void* const* d_in, const int* in_sizes, int n_in,
                              void* d_out, int out_size, void* d_ws, size_t ws_size,
                              hipStream_t stream) {
    const float* x  = (const float*)d_in[0];
    const float* bx = (const float*)d_in[1];
    const float* Wi = (const float*)d_in[2];
    const float* Wh = (const float*)d_in[3];
    const float* Wo = (const float*)d_in[4];
    const float* bo = (const float*)d_in[5];
    const int* esrc = (const int*)d_in[6];
    const int* edst = (const int*)d_in[7];
    float* out = (float*)d_out;

    int E  = in_sizes[1] / BF;
    int Eh = E / 2;
    int NM = out_size / HID;
    (void)d_ws; (void)ws_size; (void)n_in;

    k_prep<<<640, 256, 0, stream>>>(Wi, Wh, Wo);
    k_mpnn<<<NM, 256, 0, stream>>>(x, bx, bo, esrc, edst, out, Eh);
}